// Round 6
// baseline (248.794 us; speedup 1.0000x reference)
//
#include <hip/hip_runtime.h>

// z[b,d] = x[b,d] * (1 + sum_{i=1..K} w[i-1,d] * x[b,(d+i) mod D])
// B=8192, D=4096, K=16, fp32. HBM floor: ~204 MB real traffic -> ~32 us.
//
// R2 (86 us): LDS one-shot stage + __syncthreads: stage drain exposed.
// R6 (86 us): LDS double-buffer + __syncthreads: NO GAIN. VGPR=60 -> wv
//   remat'd in-loop (w latency on critical path), and __syncthreads'
//   vmcnt(0) drains the 4 JUST-ISSUED stores (~300-700cy ack) every tile.
//   Both schedules expose ~one memory latency per tile -> same 86 us.
// R7 (this): T3/T4 counted waits (m201-verified pattern).
//   - raw s_barrier + asm "s_waitcnt vmcnt(4)": drains ONLY the previous
//     stage (oldest 5 ops); this tile's 4 stores (newest) stay in flight
//     across the barrier. Stage(t+1) gets a full compute phase to land.
//   - every wave issues exactly 5 global_load_lds per tile (4 row-quarters
//     + 1 halo inst into a contiguous halo region, dummy lanes padded) so
//     vmcnt counts are wave-uniform.
//   - wv[16] pinned live via asm INSIDE the loop (R5's one-shot pin got
//     spilled; in-loop pins force liveness across iterations).

#define D 4096
#define DG 1024          // D/4 float4 column-groups per row
#define K 16
#define TPB 256
#define TILE_B 4         // rows per tile
#define NT 8             // tiles per block -> 32 rows/block
#define ROWS_PER_BLK (TILE_B * NT)
#define BUF_F4 (TILE_B * 256)   // float4s per row buffer [4][256]
#define HALO_F4 64              // 16 real halo float4s + 48 scratch

typedef float f32x4 __attribute__((ext_vector_type(4)));

__global__ __launch_bounds__(TPB) void quad_enhancer_kernel(
    const float* __restrict__ x, const float* __restrict__ w,
    float* __restrict__ out) {
  // [2][4][256] row buffers + [2][64] halo buffers -> 34816 B, 4 blocks/CU
  __shared__ float4 ldsbuf[2 * BUF_F4 + 2 * HALO_F4];

  const int tid = threadIdx.x;
  const int lane = tid & 63;
  const int cg0 = blockIdx.x * TPB;
  const int cg = cg0 + tid;
  const int b0 = blockIdx.y * ROWS_PER_BLK;

  const float4* __restrict__ x4 = (const float4*)x;
  const float4* __restrict__ w4 = (const float4*)w;
  float4* __restrict__ o4 = (float4*)out;

  float4* const buf0 = &ldsbuf[0];
  float4* const buf1 = &ldsbuf[BUF_F4];
  float4* const halo0 = &ldsbuf[2 * BUF_F4];
  float4* const halo1 = &ldsbuf[2 * BUF_F4 + HALO_F4];

  // Halo: lane l<16 loads row (l>>2), wrapped group cg0+256+(l&3).
  const int hrow = lane >> 2;
  const int hcol = (cg0 + 256 + (lane & 3)) & (DG - 1);

  // Stage tile t: 4 row-quarter gld_lds per wave + 1 halo gld_lds.
  // Exactly 5 vmem insts per wave -> uniform vmcnt bookkeeping.
  auto stage = [&](int t, float4* buf, float4* halo) {
    const int bb = b0 + t * TILE_B;
#pragma unroll
    for (int r = 0; r < TILE_B; ++r) {
      const float4* gptr = &x4[(size_t)(bb + r) * DG + cg];
      __builtin_amdgcn_global_load_lds(
          (const __attribute__((address_space(1))) void*)gptr,
          (__attribute__((address_space(3))) void*)&buf[r * 256 + tid],
          16, 0, 0);
    }
    // All 64 lanes active (uniform exec): 16 real + 48 dummy (in-bounds,
    // value unused; redundant same-value writes across waves are benign).
    const float4* hptr = (lane < 16) ? &x4[(size_t)(bb + hrow) * DG + hcol]
                                     : &x4[(size_t)bb * DG + cg];
    __builtin_amdgcn_global_load_lds(
        (const __attribute__((address_space(1))) void*)hptr,
        (__attribute__((address_space(3))) void*)&halo[lane], 16, 0, 0);
  };

  // ---- prologue: stage tile 0, load wv, drain once ----
  stage(0, buf0, halo0);

  float4 wv[K];
#pragma unroll
  for (int i = 0; i < K; ++i) wv[i] = w4[i * DG + cg];

  asm volatile("s_waitcnt vmcnt(0)" ::: "memory");  // one-time full drain

#pragma unroll 1
  for (int t = 0; t < NT; ++t) {
    // Drain previous stage only: oldest 5 = stage(t); newest 4 = stores
    // from iter t-1, which remain in flight across the barrier.
    asm volatile("s_waitcnt vmcnt(4)" ::: "memory");
    __builtin_amdgcn_s_barrier();
    asm volatile("" ::: "memory");  // compiler fence: no load hoist past bar

    // Pin wv live EVERY iteration -> remat/spill impossible across the
    // stage loop (R3: remat at VGPR=68; R5: spill at VGPR=60).
#pragma unroll
    for (int i = 0; i < K; ++i) {
      asm volatile("" : "+v"(wv[i].x), "+v"(wv[i].y), "+v"(wv[i].z),
                        "+v"(wv[i].w));
    }

    float4* const bufp = (t & 1) ? buf1 : buf0;
    float4* const halop = (t & 1) ? halo1 : halo0;
    if (t + 1 < NT) stage(t + 1, (t & 1) ? buf0 : buf1,
                          (t & 1) ? halo0 : halo1);

    // Compute tile t from bufp (wv in regs, x from LDS).
#pragma unroll 2
    for (int r = 0; r < TILE_B; ++r) {
      float xs[20];
#pragma unroll
      for (int j = 0; j < 5; ++j) {
        const int g = tid + j;
        float4 v = (g < 256) ? bufp[r * 256 + g]
                             : halop[(r << 2) + (g - 256)];
        xs[4 * j + 0] = v.x;
        xs[4 * j + 1] = v.y;
        xs[4 * j + 2] = v.z;
        xs[4 * j + 3] = v.w;
      }
      float ax = 1.0f, ay = 1.0f, az = 1.0f, aw = 1.0f;
#pragma unroll
      for (int i = 0; i < K; ++i) {
        ax = fmaf(wv[i].x, xs[i + 1], ax);
        ay = fmaf(wv[i].y, xs[i + 2], ay);
        az = fmaf(wv[i].z, xs[i + 3], az);
        aw = fmaf(wv[i].w, xs[i + 4], aw);
      }
      float4 o;
      o.x = xs[0] * ax;
      o.y = xs[1] * ay;
      o.z = xs[2] * az;
      o.w = xs[3] * aw;
      o4[(size_t)(b0 + t * TILE_B + r) * DG + cg] = o;  // stays in flight
    }
  }
}

extern "C" void kernel_launch(void* const* d_in, const int* in_sizes, int n_in,
                              void* d_out, int out_size, void* d_ws, size_t ws_size,
                              hipStream_t stream) {
  const float* x = (const float*)d_in[0];
  const float* w = (const float*)d_in[1];
  float* out = (float*)d_out;
  const int B = in_sizes[0] / D;  // 8192

  dim3 grid(DG / TPB, B / ROWS_PER_BLK);  // (4, 256) = 1024 blocks, 4/CU
  quad_enhancer_kernel<<<grid, TPB, 0, stream>>>(x, w, out);
}